// Round 1
// baseline (1363.220 us; speedup 1.0000x reference)
//
#include <hip/hip_runtime.h>

// Guided filter, r=8, eps=1e-4, input (1,3,4096,4096) fp32.
// Fused single kernel: vertical running box-sums -> LDS -> horizontal running
// box-sums -> finalize. No workspace needed.

#define HH 4096
#define WW 4096
#define CC 3
#define RAD 8
#define TX 240           // output columns per tile
#define TY 16            // output rows per tile
#define NT 256           // threads = TX + 2*RAD columns

__global__ __launch_bounds__(256, 2)
void guided_filter_kernel(const float* __restrict__ gi,
                          const float* __restrict__ gp,
                          float* __restrict__ gq) {
    // 4 * 16 * 256 * 4B = 64 KB LDS
    __shared__ float vi [TY][NT];
    __shared__ float vp [TY][NT];
    __shared__ float vpi[TY][NT];
    __shared__ float vii[TY][NT];

    const int t  = threadIdx.x;
    const int c  = blockIdx.z;
    const int x0 = blockIdx.x * TX;
    const int y0 = blockIdx.y * TY;
    const size_t plane = (size_t)HH * WW;
    const float* Ic = gi + (size_t)c * plane;
    const float* Pc = gp + (size_t)c * plane;
    float*       Qc = gq + (size_t)c * plane;

    // ---- Stage 1: vertical sliding 17-row sums for column gx ----
    const int gx = x0 - RAD + t;
    const bool vx = (gx >= 0) && (gx < WW);
    float si = 0.f, sp = 0.f, spi = 0.f, sii = 0.f;
    if (vx) {
#pragma unroll
        for (int dy = -RAD; dy <= RAD; ++dy) {
            int y = y0 + dy;
            if (y >= 0 && y < HH) {
                float a = Ic[(size_t)y * WW + gx];
                float b = Pc[(size_t)y * WW + gx];
                si += a; sp += b; spi += a * b; sii += a * a;
            }
        }
    }
    vi[0][t] = si; vp[0][t] = sp; vpi[0][t] = spi; vii[0][t] = sii;
#pragma unroll
    for (int ty = 1; ty < TY; ++ty) {
        if (vx) {
            int ya = y0 + ty + RAD;       // incoming row
            int ys = y0 + ty - 1 - RAD;   // outgoing row
            if (ya < HH) {
                float a = Ic[(size_t)ya * WW + gx];
                float b = Pc[(size_t)ya * WW + gx];
                si += a; sp += b; spi += a * b; sii += a * a;
            }
            if (ys >= 0) {
                float a = Ic[(size_t)ys * WW + gx];
                float b = Pc[(size_t)ys * WW + gx];
                si -= a; sp -= b; spi -= a * b; sii -= a * a;
            }
        }
        vi[ty][t] = si; vp[ty][t] = sp; vpi[ty][t] = spi; vii[ty][t] = sii;
    }
    __syncthreads();

    // ---- Stage 2: horizontal sliding 17-col sums + finalize ----
    // thread -> (row ty, 15-wide output segment seg)
    const int ty  = t >> 4;
    const int seg = t & 15;
    const int y   = y0 + ty;
    const int oxBase = seg * 15;     // local output col start (0..225)

    // init window for ox = oxBase: LDS cols [ox, ox+16]
    float hi = 0.f, hp = 0.f, hpi = 0.f, hii = 0.f;
#pragma unroll
    for (int k = 0; k < 17; ++k) {
        int lx = oxBase + k;
        hi  += vi [ty][lx];
        hp  += vp [ty][lx];
        hpi += vpi[ty][lx];
        hii += vii[ty][lx];
    }
    const int ny = min(y + RAD, HH - 1) - max(y - RAD, 0) + 1;
#pragma unroll
    for (int j = 0; j < 15; ++j) {
        int ox = oxBase + j;
        int x  = x0 + ox;
        if (j) {
            int ca = ox + 16, cs = ox - 1;
            hi  += vi [ty][ca] - vi [ty][cs];
            hp  += vp [ty][ca] - vp [ty][cs];
            hpi += vpi[ty][ca] - vpi[ty][cs];
            hii += vii[ty][ca] - vii[ty][cs];
        }
        if (x < WW) {
            int nx = min(x + RAD, WW - 1) - max(x - RAD, 0) + 1;
            float invN = 1.0f / (float)(nx * ny);
            float mi  = hi  * invN;
            float mp  = hp  * invN;
            float mpi = hpi * invN;
            float mii = hii * invN;
            float cov_ip = mpi - mp * mi;
            float cov_ii = mii - mi * mi;
            float a = cov_ip / (cov_ii + 1e-4f);
            float b = mp - a * mi;
            float iv = Ic[(size_t)y * WW + x];
            float q = a * iv + b;
            q = fminf(fmaxf(q, 0.0f), 1.0f);
            Qc[(size_t)y * WW + x] = q;
        }
    }
}

extern "C" void kernel_launch(void* const* d_in, const int* in_sizes, int n_in,
                              void* d_out, int out_size, void* d_ws, size_t ws_size,
                              hipStream_t stream) {
    const float* gi = (const float*)d_in[0];
    const float* gp = (const float*)d_in[1];
    float* gq = (float*)d_out;
    dim3 grid((WW + TX - 1) / TX, HH / TY, CC);
    guided_filter_kernel<<<grid, dim3(NT), 0, stream>>>(gi, gp, gq);
}

// Round 2
// 537.047 us; speedup vs baseline: 2.5384x; 2.5384x over previous
//
#include <hip/hip_runtime.h>

// Guided filter r=8, eps=1e-4, (1,3,4096,4096) fp32.
// Wave-autonomous streaming: no LDS tiles, no barriers.
//  - lane = column (48 outputs + 2*8 halo per 64-lane wave)
//  - vertical 17-row running sums in registers (17-row register circular
//    buffer of I,P; inner 17-iter loop fully unrolled -> constant indices)
//  - horizontal 17-tap box sum via wave-wide DPP inclusive scan +
//    2 ds_bpermute taps per quantity

#define HH   4096
#define WW   4096
#define CC   3
#define RAD  8
#define LOG2W 12
#define OUTW 48            // output columns per wave
#define ROWS 69            // output rows per wave tile (1 + 4*17)
#define CS   86            // ceil(4096/48) column strips
#define RS   60            // ceil(4096/69) row strips
#define WPB  4             // waves per 256-thread block
#define EPS  1e-4f

// x += value selected by DPP (invalid/masked lanes contribute 0)
template <int CTRL, int RM, int BM>
__device__ __forceinline__ float dpp_add(float x) {
    int t = __builtin_amdgcn_update_dpp(0, __float_as_int(x), CTRL, RM, BM, false);
    return x + __int_as_float(t);
}

// wave64 inclusive prefix sum (Hillis-Steele via DPP, VALU-rate)
__device__ __forceinline__ float wave_iscan(float x) {
    x = dpp_add<0x111, 0xF, 0xF>(x);   // row_shr:1
    x = dpp_add<0x112, 0xF, 0xF>(x);   // row_shr:2
    x = dpp_add<0x114, 0xF, 0xF>(x);   // row_shr:4
    x = dpp_add<0x118, 0xF, 0xF>(x);   // row_shr:8
    x = dpp_add<0x142, 0xA, 0xF>(x);   // row_bcast:15 -> rows 1,3
    x = dpp_add<0x143, 0xC, 0xF>(x);   // row_bcast:31 -> rows 2,3
    return x;
}

// 17-wide window sum from inclusive prefix: Pref[l+8] - Pref[l-9]
__device__ __forceinline__ float win17(float pref, int a_dn, int a_up, bool hasup) {
    float dn = __int_as_float(__builtin_amdgcn_ds_bpermute(a_dn, __float_as_int(pref)));
    float up = __int_as_float(__builtin_amdgcn_ds_bpermute(a_up, __float_as_int(pref)));
    return dn - (hasup ? up : 0.0f);
}

__global__ __launch_bounds__(256, 6)
void gf_stream_kernel(const float* __restrict__ gi,
                      const float* __restrict__ gp,
                      float* __restrict__ gq) {
    const int lane = threadIdx.x & 63;
    const int wid  = blockIdx.x * WPB + (threadIdx.x >> 6);

    const int c   = wid / (CS * RS);
    const int rm  = wid - c * (CS * RS);
    const int rs  = rm / CS;
    const int cs  = rm - rs * CS;
    const int x0  = cs * OUTW;
    const int y0  = rs * ROWS;

    const size_t plane = (size_t)HH << LOG2W;
    const float* Ic = gi + (size_t)c * plane;
    const float* Pc = gp + (size_t)c * plane;
    float*       Qc = gq + (size_t)c * plane;

    const int  gx    = x0 - RAD + lane;
    const bool colok = (gx >= 0) && (gx < WW);
    const int  gxc   = min(max(gx, 0), WW - 1);
    const bool outl  = (lane >= RAD) && (lane < RAD + OUTW) && (gx < WW);
    const int  a_dn  = ((lane + RAD) & 63) << 2;
    const int  a_up  = ((lane - RAD - 1) & 63) << 2;
    const bool hasup = (lane >= RAD + 1);

    const int   nx     = min(gx + RAD, WW - 1) - max(gx - RAD, 0) + 1;
    const float inv_nx = __builtin_amdgcn_rcpf((float)max(nx, 1));

    float bi[17], bp[17];
    float si = 0.f, sp = 0.f, spi = 0.f, sii = 0.f;

    // ---- init: rows y0-8 .. y0+8 into circular buffer slots 0..16 ----
#pragma unroll
    for (int k = 0; k < 17; ++k) {
        int y = y0 - RAD + k;
        float a = 0.f, b = 0.f;
        if (y >= 0 && y < HH) {           // wave-uniform branch
            unsigned idx = ((unsigned)y << LOG2W) + (unsigned)gxc;
            float av = Ic[idx];
            float bv = Pc[idx];
            a = colok ? av : 0.f;
            b = colok ? bv : 0.f;
        }
        bi[k] = a; bp[k] = b;
        si += a; sp += b; spi += a * b; sii += a * a;
    }

    // ---- emit one output row from current vertical sums ----
    auto emit = [&](int y, float icur) {
        float Si  = wave_iscan(si);
        float Sp  = wave_iscan(sp);
        float Spi = wave_iscan(spi);
        float Sii = wave_iscan(sii);
        float wi  = win17(Si,  a_dn, a_up, hasup);
        float wp  = win17(Sp,  a_dn, a_up, hasup);
        float wpi = win17(Spi, a_dn, a_up, hasup);
        float wii = win17(Sii, a_dn, a_up, hasup);

        int   ny   = min(y + RAD, HH - 1) - max(y - RAD, 0) + 1;
        float invN = inv_nx * __builtin_amdgcn_rcpf((float)ny);
        float mi   = wi  * invN;
        float mp   = wp  * invN;
        float mpi  = wpi * invN;
        float mii  = wii * invN;
        float cip  = mpi - mp * mi;
        float cii  = mii - mi * mi;
        float a    = cip * __builtin_amdgcn_rcpf(cii + EPS);
        float b    = mp - a * mi;
        float q    = fminf(fmaxf(fmaf(a, icur, b), 0.f), 1.f);
        if (outl && y < HH) {
            unsigned oidx = ((unsigned)y << LOG2W) + (unsigned)gx;
            Qc[oidx] = q;
        }
    };

    emit(y0, bi[8]);                      // t = 0 (current row slot = 8)

    int y = y0;
#pragma unroll 1
    for (int o = 0; o < 4; ++o) {
#pragma unroll
        for (int u = 0; u < 17; ++u) {
            ++y;                          // y = y0 + t, t = 1 + 17*o + u
            // outgoing row (y-9) lives in slot u; incoming row (y+8) reuses it
            float a0 = bi[u], b0 = bp[u];
            si -= a0; sp -= b0;
            spi = fmaf(-a0, b0, spi);
            sii = fmaf(-a0, a0, sii);

            int yin = y + RAD;
            float a = 0.f, b = 0.f;
            if (yin < HH) {               // wave-uniform; yin >= 9 always
                unsigned idx = ((unsigned)yin << LOG2W) + (unsigned)gxc;
                float av = Ic[idx];
                float bv = Pc[idx];
                a = colok ? av : 0.f;
                b = colok ? bv : 0.f;
            }
            bi[u] = a; bp[u] = b;
            si += a; sp += b;
            spi = fmaf(a, b, spi);
            sii = fmaf(a, a, sii);

            emit(y, bi[(u + 9) % 17]);    // current row y sits in slot (u+9)%17
        }
    }
}

extern "C" void kernel_launch(void* const* d_in, const int* in_sizes, int n_in,
                              void* d_out, int out_size, void* d_ws, size_t ws_size,
                              hipStream_t stream) {
    const float* gi = (const float*)d_in[0];
    const float* gp = (const float*)d_in[1];
    float* gq = (float*)d_out;
    const int total_waves = CC * CS * RS;          // 15480
    const int blocks = total_waves / WPB;          // 3870
    gf_stream_kernel<<<blocks, 256, 0, stream>>>(gi, gp, gq);
}